// Round 9
// baseline (85.254 us; speedup 1.0000x reference)
//
#include <hip/hip_runtime.h>

#define BATCH 512
#define T 256
#define C 384
#define H 64

typedef __bf16 bf16x8 __attribute__((ext_vector_type(8)));
typedef __bf16 bf16x4 __attribute__((ext_vector_type(4)));
typedef float f32x4 __attribute__((ext_vector_type(4)));

// ws layout (bytes): wT @0 (147456); wsQ @147456; wsK @+16MB; wsV @+32MB. total 50479104.
// wsQ/wsK: per (batch, tile 0..15, ks 0..1): 64 lanes x 16B MFMA fragments.
//   wsQ8[((b*16+t)*2+ks)*64 + lane] : lane(l15,g) = Q[t*16+l15][ks*32+g*8 .. +8]  (A-frag)
//   wsK8 same                        : lane(l15,g) = K[t*16+l15][ks*32+g*8 .. +8]  (B-frag)
// wsV: V^T row-major [b][64 h][256 t] bf16 (unswizzled).
#define WT_BYTES  147456
#define QKV_BYTES 16777216

// wT: MFMA B-fragments in lane order. frag fi = ((kt*2+ks)*3+m)*4+n,
// 64 lanes x 16B; lane(l15,g) holds W^T[h=n*16+l15][k=kt*64+ks*32+g*8 ..+8].
__global__ void prep_w(const float* __restrict__ Wq, const float* __restrict__ Wk,
                       const float* __restrict__ Wv, __bf16* __restrict__ wT) {
    const int tid = blockIdx.x * 256 + threadIdx.x;   // 9216 threads
    if (tid >= 9216) return;
    const int lane = tid & 63;
    const int f    = tid >> 6;
    const int n    = f & 3;
    const int f2   = f >> 2;
    const int m    = f2 % 3;
    const int kk   = f2 / 3;
    const int l15  = lane & 15;
    const int g    = lane >> 4;
    const int h    = n * 16 + l15;
    const int k0   = kk * 32 + g * 8;
    const float* W = (m == 0) ? Wq : (m == 1) ? Wk : Wv;
    bf16x8 v;
#pragma unroll
    for (int j = 0; j < 8; ++j) v[j] = (__bf16)W[(k0 + j) * H + h];
    reinterpret_cast<bf16x8*>(wT)[tid] = v;
}

// ---------------- Kernel A: projections, half-batch per block ----------------
// LDS 40KB: XS @0 (16KB) [128 r][64 c] bf16 swz ^((r&7)<<4); WF @16384 (24KB) frags.
// Wave w's XS slice [w*2048, +2048) is written AND read only by wave w -> scr-safe.
#define A_XS 0
#define A_WF 16384
#define A_LDS 40960

__global__ __launch_bounds__(512, 4) void proj_qkv(
    const float* __restrict__ x, const __bf16* __restrict__ wT,
    bf16x8* __restrict__ wsQ8, bf16x8* __restrict__ wsK8, __bf16* __restrict__ wsV)
{
    __shared__ __align__(16) unsigned char lds[A_LDS];
    const int tid  = threadIdx.x;
    const int w    = tid >> 6;
    const int lane = tid & 63;
    const int l15  = lane & 15;
    const int g    = lane >> 4;
    const int b    = blockIdx.x >> 1;
    const int half = blockIdx.x & 1;
    const float* xb = x + (size_t)b * T * C + (size_t)half * 128 * C;
    const bf16x8* wTv = reinterpret_cast<const bf16x8*>(wT);

    f32x4 acc[3][4];
#pragma unroll
    for (int m = 0; m < 3; ++m)
#pragma unroll
        for (int n = 0; n < 4; ++n)
            acc[m][n] = (f32x4){0.f, 0.f, 0.f, 0.f};

    const int xrow = tid >> 2;            // 0..127
    const int xc0  = (tid & 3) << 4;      // elem col 0,16,32,48
    float4 px[4];
    bf16x8 pw[3];

    auto loadX = [&](int kt) {
        const float* s_ = xb + xrow * C + kt * 64 + xc0;
#pragma unroll
        for (int q = 0; q < 4; ++q) px[q] = *reinterpret_cast<const float4*>(s_ + 4 * q);
    };
    auto loadW = [&](int kt) {
#pragma unroll
        for (int ri = 0; ri < 3; ++ri) pw[ri] = wTv[kt * 1536 + (ri << 9) + tid];
    };

    loadX(0);
    loadW(0);

#pragma unroll 1
    for (int kt = 0; kt < 6; ++kt) {
        // stage X (2 x bf16x8) and W frags (3 x 16B)
        {
            bf16x8 v0, v1;
#pragma unroll
            for (int j = 0; j < 4; ++j) {
                v0[j] = (__bf16)px[0][j]; v0[j + 4] = (__bf16)px[1][j];
                v1[j] = (__bf16)px[2][j]; v1[j + 4] = (__bf16)px[3][j];
            }
            const int sw_ = (xrow & 7) << 4;
            *reinterpret_cast<bf16x8*>(lds + A_XS + xrow * 128 + ((2 * xc0) ^ sw_)) = v0;
            *reinterpret_cast<bf16x8*>(lds + A_XS + xrow * 128 + ((2 * xc0 + 16) ^ sw_)) = v1;
#pragma unroll
            for (int ri = 0; ri < 3; ++ri)
                *reinterpret_cast<bf16x8*>(lds + A_WF + (((ri << 9) + tid) << 4)) = pw[ri];
        }
        if (kt < 5) { loadX(kt + 1); loadW(kt + 1); }
        __syncthreads();

        bf16x8 af[2];
        const int row = (w << 4) + l15;
#pragma unroll
        for (int ks = 0; ks < 2; ++ks)
            af[ks] = *reinterpret_cast<const bf16x8*>(
                lds + A_XS + row * 128 + (((ks << 6) + (g << 4)) ^ ((row & 7) << 4)));
#pragma unroll
        for (int ks = 0; ks < 2; ++ks)
#pragma unroll
            for (int m = 0; m < 3; ++m)
#pragma unroll
                for (int n = 0; n < 4; ++n) {
                    const int fl = ((ks * 3 + m) << 2) + n;
                    const bf16x8 bfr = *reinterpret_cast<const bf16x8*>(
                        lds + A_WF + (fl << 10) + (lane << 4));
                    acc[m][n] = __builtin_amdgcn_mfma_f32_16x16x32_bf16(af[ks], bfr, acc[m][n], 0, 0, 0);
                }
        __syncthreads();
    }

    // epilogue. D layout: h = n*16+l15 (col), t-in-tile = g*4+r (row).
    const int gt = (half << 3) + w;     // global tile 0..15
    const int tb = gt << 4;

    // V^T: packed 8B stores, [b][h][t]
#pragma unroll
    for (int n = 0; n < 4; ++n) {
        const int hcol = (n << 4) + l15;
        bf16x4 pv;
#pragma unroll
        for (int r = 0; r < 4; ++r) pv[r] = (__bf16)acc[2][n][r];
        *reinterpret_cast<bf16x4*>(wsV + (size_t)b * 16384 + hcol * 256 + tb + (g << 2)) = pv;
    }
    // K and Q: transpose via wave-own scr (= own XS slice), emit pre-swizzled frags
    unsigned char* scr = lds + A_XS + (w << 11);
#pragma unroll
    for (int m = 0; m < 2; ++m) {       // m=0: K (acc[1]), m=1: Q (acc[0])
        const f32x4* a = (m == 0) ? acc[1] : acc[0];
        bf16x8* dst = (m == 0) ? wsK8 : wsQ8;
#pragma unroll
        for (int n = 0; n < 4; ++n)
#pragma unroll
            for (int r = 0; r < 4; ++r) {
                const int row = (g << 2) + r;
                *reinterpret_cast<__bf16*>(
                    scr + row * 128 + ((2 * ((n << 4) + l15)) ^ ((row & 7) << 4))) = (__bf16)a[n][r];
            }
#pragma unroll
        for (int ks = 0; ks < 2; ++ks) {
            const bf16x8 fr = *reinterpret_cast<const bf16x8*>(
                scr + l15 * 128 + (((ks << 6) + (g << 4)) ^ ((l15 & 7) << 4)));
            dst[(((size_t)b * 16 + gt) * 2 + ks) * 64 + lane] = fr;
        }
    }
}

// ---------------- Kernel B: attention, zero barriers ----------------
__global__ __launch_bounds__(512, 4) void attn(
    const bf16x8* __restrict__ wsQ8, const bf16x8* __restrict__ wsK8,
    const __bf16* __restrict__ wsV, float* __restrict__ out)
{
    __shared__ __align__(16) unsigned char lds[16384];   // 8 waves x 2KB P-stage
    const int tid  = threadIdx.x;
    const int w    = tid >> 6;
    const int lane = tid & 63;
    const int l15  = lane & 15;
    const int g    = lane >> 4;
    const int b    = blockIdx.x;
    unsigned char* scr = lds + (w << 11);
    const float se = 0.051031036307982884f * 1.4426950408889634f;  // 384^-0.5 * log2(e)

    const int tile0 = w, tile1 = 15 - w;   // causal-balanced pair
    bf16x8 qf[2][2];
#pragma unroll
    for (int j = 0; j < 2; ++j) {
        const int mt = (j == 0) ? tile0 : tile1;
#pragma unroll
        for (int ks = 0; ks < 2; ++ks)
            qf[j][ks] = wsQ8[(((size_t)b * 16 + mt) * 2 + ks) * 64 + lane];
    }

    auto attend = [&](int mt, bf16x8 qfa, bf16x8 qfb) {
        const int mtu  = __builtin_amdgcn_readfirstlane(mt);
        const int q0   = mt << 4;
        const int qrow = q0 + (g << 2);

        f32x4 o[4];
#pragma unroll
        for (int nh = 0; nh < 4; ++nh) o[nh] = (f32x4){0.f, 0.f, 0.f, 0.f};
        float ssum[4] = {0.f, 0.f, 0.f, 0.f};

#pragma unroll
        for (int kc = 0; kc < 4; ++kc) {
            if (kc <= (mtu >> 2)) {     // wave-uniform causal skip
                f32x4 sb[4];
#pragma unroll
                for (int n4 = 0; n4 < 4; ++n4) sb[n4] = (f32x4){0.f, 0.f, 0.f, 0.f};
#pragma unroll
                for (int ks4 = 0; ks4 < 2; ++ks4) {
                    const bf16x8 qv = (ks4 == 0) ? qfa : qfb;
#pragma unroll
                    for (int n4 = 0; n4 < 4; ++n4) {
                        const bf16x8 bfr =
                            wsK8[(((size_t)b * 16 + (kc << 2) + n4) * 2 + ks4) * 64 + lane];
                        sb[n4] = __builtin_amdgcn_mfma_f32_16x16x32_bf16(qv, bfr, sb[n4], 0, 0, 0);
                    }
                }
                // p = exp(s*scale); no max-sub (normalization cancels, |s*scale| small). mask, stage.
#pragma unroll
                for (int n4 = 0; n4 < 4; ++n4) {
                    const int k = (kc << 6) + (n4 << 4) + l15;
#pragma unroll
                    for (int r = 0; r < 4; ++r) {
                        float p = exp2f(sb[n4][r] * se);
                        if (k > qrow + r) p = 0.f;
                        ssum[r] += p;
                        const int prow = (g << 2) + r;
                        *reinterpret_cast<__bf16*>(
                            scr + prow * 128 + ((2 * ((n4 << 4) + l15)) ^ ((prow & 7) << 4))) = (__bf16)p;
                    }
                }
#pragma unroll
                for (int ks4 = 0; ks4 < 2; ++ks4) {
                    const bf16x8 pf = *reinterpret_cast<const bf16x8*>(
                        scr + l15 * 128 + (((ks4 << 6) + (g << 4)) ^ ((l15 & 7) << 4)));
#pragma unroll
                    for (int nh = 0; nh < 4; ++nh) {
                        // element offsets into V^T row: t = kc*64 + ks4*32 + g*8
                        const bf16x8 vb = *reinterpret_cast<const bf16x8*>(
                            wsV + (size_t)b * 16384 + ((nh << 4) + l15) * 256 +
                            (kc << 6) + (ks4 << 5) + (g << 3));
                        o[nh] = __builtin_amdgcn_mfma_f32_16x16x32_bf16(pf, vb, o[nh], 0, 0, 0);
                    }
                }
            }
        }

#pragma unroll
        for (int d = 1; d < 16; d <<= 1)
#pragma unroll
            for (int r = 0; r < 4; ++r)
                ssum[r] += __shfl_xor(ssum[r], d);

        float inv[4];
#pragma unroll
        for (int r = 0; r < 4; ++r) inv[r] = 1.0f / ssum[r];
        float* ob = out + ((size_t)b * T + q0) * H;
#pragma unroll
        for (int nh = 0; nh < 4; ++nh)
#pragma unroll
            for (int r = 0; r < 4; ++r)
                ob[((g << 2) + r) * H + (nh << 4) + l15] = o[nh][r] * inv[r];
    };

    attend(tile0, qf[0][0], qf[0][1]);
    attend(tile1, qf[1][0], qf[1][1]);
}

// ---------------- Fallback: round-5 fused kernel (known-good 60.9 us) ----------------
#define XS_OFF 0
#define KS_OFF 0
#define WF_OFF 32768
#define VT_OFF 32768
#define SCR_OFF 65536
#define LDS_BYTES 81920

template <bool USE_WT>
__global__ __launch_bounds__(512, 2) void head_fused(
    const float* __restrict__ x, const float* __restrict__ Wq,
    const float* __restrict__ Wk, const float* __restrict__ Wv,
    const __bf16* __restrict__ wT, float* __restrict__ out)
{
    __shared__ __align__(16) unsigned char lds[LDS_BYTES];
    const int tid  = threadIdx.x;
    const int w    = tid >> 6;
    const int lane = tid & 63;
    const int l15  = lane & 15;
    const int g    = lane >> 4;
    const int b    = blockIdx.x;
    const float* xb = x + (size_t)b * T * C;
    const float* wm[3] = {Wq, Wk, Wv};
    const bf16x8* wTv = reinterpret_cast<const bf16x8*>(wT);

    const int tile0 = w;
    const int tile1 = 15 - w;

    f32x4 acc[3][2][4];
#pragma unroll
    for (int m = 0; m < 3; ++m)
#pragma unroll
        for (int j = 0; j < 2; ++j)
#pragma unroll
            for (int n = 0; n < 4; ++n)
                acc[m][j][n] = (f32x4){0.f, 0.f, 0.f, 0.f};

    float4 px[8];
    bf16x8 pw[3];
    const int xrow0 = tid >> 3;
    const int xc0   = (tid & 7) << 3;

    auto loadX = [&](int kt) {
#pragma unroll
        for (int ri = 0; ri < 4; ++ri) {
            const float* src = xb + (xrow0 + (ri << 6)) * C + kt * 64 + xc0;
            px[2 * ri]     = *reinterpret_cast<const float4*>(src);
            px[2 * ri + 1] = *reinterpret_cast<const float4*>(src + 4);
        }
    };
    auto loadW = [&](int kt) {
        if (USE_WT) {
#pragma unroll
            for (int ri = 0; ri < 3; ++ri)
                pw[ri] = wTv[kt * 1536 + (ri << 9) + tid];
        } else {
#pragma unroll
            for (int ri = 0; ri < 3; ++ri) {
                const int s  = (ri << 9) + tid;
                const int fl = s >> 6, ls = s & 63;
                const int n = fl & 3, q = fl >> 2, m = q % 3, ks = q / 3;
                const int k0 = kt * 64 + ks * 32 + ((ls >> 4) << 3);
                const int h  = (n << 4) + (ls & 15);
                bf16x8 v;
#pragma unroll
                for (int j = 0; j < 8; ++j) v[j] = (__bf16)wm[m][(k0 + j) * H + h];
                pw[ri] = v;
            }
        }
    };

    loadX(0);
    loadW(0);

#pragma unroll 1
    for (int kt = 0; kt < 6; ++kt) {
#pragma unroll
        for (int ri = 0; ri < 4; ++ri) {
            const int row = xrow0 + (ri << 6);
            bf16x8 v;
#pragma unroll
            for (int j = 0; j < 8; ++j)
                v[j] = (__bf16)((j < 4) ? px[2 * ri][j] : px[2 * ri + 1][j - 4]);
            *reinterpret_cast<bf16x8*>(
                lds + XS_OFF + row * 128 + ((2 * xc0) ^ ((row & 7) << 4))) = v;
        }
#pragma unroll
        for (int ri = 0; ri < 3; ++ri)
            *reinterpret_cast<bf16x8*>(lds + WF_OFF + (((ri << 9) + tid) << 4)) = pw[ri];

        if (kt < 5) { loadX(kt + 1); loadW(kt + 1); }
        __syncthreads();

        bf16x8 af[2][2];
#pragma unroll
        for (int j = 0; j < 2; ++j) {
            const int row = ((j == 0) ? tile0 : tile1) * 16 + l15;
#pragma unroll
            for (int ks = 0; ks < 2; ++ks)
                af[j][ks] = *reinterpret_cast<const bf16x8*>(
                    lds + XS_OFF + row * 128 + (((ks << 6) + (g << 4)) ^ ((row & 7) << 4)));
        }
#pragma unroll
        for (int ks = 0; ks < 2; ++ks)
#pragma unroll
            for (int m = 0; m < 3; ++m)
#pragma unroll
                for (int n = 0; n < 4; ++n) {
                    const int fl = ((ks * 3 + m) << 2) + n;
                    const bf16x8 bfr = *reinterpret_cast<const bf16x8*>(
                        lds + WF_OFF + (fl << 10) + (lane << 4));
                    acc[m][0][n] = __builtin_amdgcn_mfma_f32_16x16x32_bf16(af[0][ks], bfr, acc[m][0][n], 0, 0, 0);
                    acc[m][1][n] = __builtin_amdgcn_mfma_f32_16x16x32_bf16(af[1][ks], bfr, acc[m][1][n], 0, 0, 0);
                }
        __syncthreads();
    }

    bf16x8 qf[2][2];
    unsigned char* scr = lds + SCR_OFF + (w << 11);
#pragma unroll
    for (int j = 0; j < 2; ++j) {
        const int tb = ((j == 0) ? tile0 : tile1) << 4;
#pragma unroll
        for (int n = 0; n < 4; ++n) {
            const int hcol = (n << 4) + l15;
            bf16x4 pv;
#pragma unroll
            for (int r = 0; r < 4; ++r) pv[r] = (__bf16)acc[2][j][n][r];
            const int trow0 = tb + (g << 2);
            *reinterpret_cast<bf16x4*>(lds + VT_OFF + hcol * 512 + ((2 * trow0) ^ ((hcol & 7) << 4))) = pv;
#pragma unroll
            for (int r = 0; r < 4; ++r) {
                const int trow = trow0 + r;
                *reinterpret_cast<__bf16*>(lds + KS_OFF + trow * 128 + ((2 * hcol) ^ ((trow & 7) << 4))) =
                    (__bf16)acc[1][j][n][r];
            }
        }
#pragma unroll
        for (int n = 0; n < 4; ++n)
#pragma unroll
            for (int r = 0; r < 4; ++r) {
                const int row = (g << 2) + r;
                *reinterpret_cast<__bf16*>(
                    scr + row * 128 + ((2 * ((n << 4) + l15)) ^ ((row & 7) << 4))) = (__bf16)acc[0][j][n][r];
            }
        qf[j][0] = *reinterpret_cast<const bf16x8*>(
            scr + l15 * 128 + (((g << 4) + 0) ^ ((l15 & 7) << 4)));
        qf[j][1] = *reinterpret_cast<const bf16x8*>(
            scr + l15 * 128 + (((g << 4) + 64) ^ ((l15 & 7) << 4)));
    }
    __syncthreads();

    const float se = 0.051031036307982884f * 1.4426950408889634f;

    auto attend = [&](int mt, bf16x8 qfa, bf16x8 qfb) {
        const int mtu = __builtin_amdgcn_readfirstlane(mt);
        const int q0  = mt << 4;
        const int qrow = q0 + (g << 2);

        f32x4 o[4];
#pragma unroll
        for (int nh = 0; nh < 4; ++nh) o[nh] = (f32x4){0.f, 0.f, 0.f, 0.f};
        float ssum[4] = {0.f, 0.f, 0.f, 0.f};

#pragma unroll
        for (int kc = 0; kc < 4; ++kc) {
            if (kc <= (mtu >> 2)) {
                f32x4 sb[4];
#pragma unroll
                for (int n4 = 0; n4 < 4; ++n4) sb[n4] = (f32x4){0.f, 0.f, 0.f, 0.f};
#pragma unroll
                for (int ks4 = 0; ks4 < 2; ++ks4) {
                    const bf16x8 qv = (ks4 == 0) ? qfa : qfb;
#pragma unroll
                    for (int n4 = 0; n4 < 4; ++n4) {
                        const int brow = (kc << 6) + (n4 << 4) + l15;
                        const bf16x8 bfr = *reinterpret_cast<const bf16x8*>(
                            lds + KS_OFF + brow * 128 + (((ks4 << 6) + (g << 4)) ^ ((brow & 7) << 4)));
                        sb[n4] = __builtin_amdgcn_mfma_f32_16x16x32_bf16(qv, bfr, sb[n4], 0, 0, 0);
                    }
                }
#pragma unroll
                for (int n4 = 0; n4 < 4; ++n4) {
                    const int k = (kc << 6) + (n4 << 4) + l15;
#pragma unroll
                    for (int r = 0; r < 4; ++r) {
                        float p = exp2f(sb[n4][r] * se);
                        if (k > qrow + r) p = 0.f;
                        ssum[r] += p;
                        const int prow = (g << 2) + r;
                        *reinterpret_cast<__bf16*>(
                            scr + prow * 128 + ((2 * ((n4 << 4) + l15)) ^ ((prow & 7) << 4))) = (__bf16)p;
                    }
                }
#pragma unroll
                for (int ks4 = 0; ks4 < 2; ++ks4) {
                    const bf16x8 pf = *reinterpret_cast<const bf16x8*>(
                        scr + l15 * 128 + (((ks4 << 6) + (g << 4)) ^ ((l15 & 7) << 4)));
#pragma unroll
                    for (int nh = 0; nh < 4; ++nh) {
                        const int hrow = (nh << 4) + l15;
                        const bf16x8 vb = *reinterpret_cast<const bf16x8*>(
                            lds + VT_OFF + hrow * 512 +
                            (((kc << 7) + (ks4 << 6) + (g << 4)) ^ ((hrow & 7) << 4)));
                        o[nh] = __builtin_amdgcn_mfma_f32_16x16x32_bf16(pf, vb, o[nh], 0, 0, 0);
                    }
                }
            }
        }

#pragma unroll
        for (int d = 1; d < 16; d <<= 1)
#pragma unroll
            for (int r = 0; r < 4; ++r)
                ssum[r] += __shfl_xor(ssum[r], d);

        float inv[4];
#pragma unroll
        for (int r = 0; r < 4; ++r) inv[r] = 1.0f / ssum[r];
        float* ob = out + ((size_t)b * T + q0) * H;
#pragma unroll
        for (int nh = 0; nh < 4; ++nh)
#pragma unroll
            for (int r = 0; r < 4; ++r)
                ob[((g << 2) + r) * H + (nh << 4) + l15] = o[nh][r] * inv[r];
    };

    attend(tile0, qf[0][0], qf[0][1]);
    attend(tile1, qf[1][0], qf[1][1]);
}

extern "C" void kernel_launch(void* const* d_in, const int* in_sizes, int n_in,
                              void* d_out, int out_size, void* d_ws, size_t ws_size,
                              hipStream_t stream) {
    (void)in_sizes; (void)n_in; (void)out_size;
    const float* x  = (const float*)d_in[0];
    const float* Wk = (const float*)d_in[1];
    const float* Wq = (const float*)d_in[2];
    const float* Wv = (const float*)d_in[3];
    float* out = (float*)d_out;
    const size_t need = (size_t)WT_BYTES + 3 * (size_t)QKV_BYTES;
    if (ws_size >= need) {
        char* p = (char*)d_ws;
        __bf16* wT   = (__bf16*)p;
        bf16x8* wsQ8 = (bf16x8*)(p + WT_BYTES);
        bf16x8* wsK8 = (bf16x8*)(p + WT_BYTES + QKV_BYTES);
        __bf16* wsV  = (__bf16*)(p + WT_BYTES + 2 * (size_t)QKV_BYTES);
        prep_w<<<dim3(36), dim3(256), 0, stream>>>(Wq, Wk, Wv, wT);
        proj_qkv<<<dim3(2 * BATCH), dim3(512), 0, stream>>>(x, wT, wsQ8, wsK8, wsV);
        attn<<<dim3(BATCH), dim3(512), 0, stream>>>(wsQ8, wsK8, wsV, out);
    } else if (ws_size >= (size_t)WT_BYTES) {
        __bf16* wT = (__bf16*)d_ws;
        prep_w<<<dim3(36), dim3(256), 0, stream>>>(Wq, Wk, Wv, wT);
        head_fused<true><<<dim3(BATCH), dim3(512), 0, stream>>>(x, Wq, Wk, Wv, wT, out);
    } else {
        head_fused<false><<<dim3(BATCH), dim3(512), 0, stream>>>(x, Wq, Wk, Wv, nullptr, out);
    }
}

// Round 10
// 62.140 us; speedup vs baseline: 1.3720x; 1.3720x over previous
//
#include <hip/hip_runtime.h>

#define BATCH 512
#define T 256
#define C 384
#define H 64

typedef __bf16 bf16x8 __attribute__((ext_vector_type(8)));
typedef __bf16 bf16x4 __attribute__((ext_vector_type(4)));
typedef float f32x4 __attribute__((ext_vector_type(4)));

// LDS byte map (144 KB).
// Phase 1: WF @0 (147456B): ALL 144 W B-frags (6 kt x 24), frag fl at fl*1024 + lane*16.
//          Staged ONCE -> phase 1 has NO barriers.
// Phase 2 (overwrites WF after one barrier):
//   Ks  @0     (32KB): K [256 t][64 h] bf16, row stride 128B, swz ^((t&7)<<4)
//   VT  @32768 (32KB): V^T [64 h][256 t] bf16, row stride 512B, swz ^((h&7)<<4)
//   SCR @65536 (16KB): 8 waves x 2KB [16][64] bf16 swz ^((row&7)<<4) (Q xpose, P stage)
#define WF_OFF 0
#define KS_OFF 0
#define VT_OFF 32768
#define SCR_OFF 65536
#define LDS_BYTES 147456

// wT layout: MFMA B-fragments in lane order. frag fi = ((kt*2+ks)*3+m)*4+n,
// 64 lanes x 16B; lane(l15,g) holds W^T[h=n*16+l15][k=kt*64+ks*32+g*8 ..+8].
__global__ void prep_w(const float* __restrict__ Wq, const float* __restrict__ Wk,
                       const float* __restrict__ Wv, __bf16* __restrict__ wT) {
    const int tid = blockIdx.x * 256 + threadIdx.x;   // 9216 threads
    if (tid >= 9216) return;
    const int lane = tid & 63;
    const int f    = tid >> 6;
    const int n    = f & 3;
    const int f2   = f >> 2;
    const int m    = f2 % 3;
    const int kk   = f2 / 3;
    const int l15  = lane & 15;
    const int g    = lane >> 4;
    const int h    = n * 16 + l15;
    const int k0   = kk * 32 + g * 8;
    const float* W = (m == 0) ? Wq : (m == 1) ? Wk : Wv;
    bf16x8 v;
#pragma unroll
    for (int j = 0; j < 8; ++j) v[j] = (__bf16)W[(k0 + j) * H + h];
    reinterpret_cast<bf16x8*>(wT)[tid] = v;
}

template <bool USE_WT>
__global__ __launch_bounds__(512, 2) void head_fused(
    const float* __restrict__ x, const float* __restrict__ Wq,
    const float* __restrict__ Wk, const float* __restrict__ Wv,
    const __bf16* __restrict__ wT, float* __restrict__ out)
{
    __shared__ __align__(16) unsigned char lds[LDS_BYTES];
    const int tid  = threadIdx.x;
    const int w    = tid >> 6;
    const int lane = tid & 63;
    const int l15  = lane & 15;
    const int g    = lane >> 4;
    const int b    = blockIdx.x;
    const float* xb = x + (size_t)b * T * C;

    const int tile0 = w;        // {w, 15-w}: phase-2 causal chunks per pair == 5 for all w
    const int tile1 = 15 - w;

    f32x4 acc[3][2][4];
#pragma unroll
    for (int m = 0; m < 3; ++m)
#pragma unroll
        for (int j = 0; j < 2; ++j)
#pragma unroll
            for (int n = 0; n < 4; ++n)
                acc[m][j][n] = (f32x4){0.f, 0.f, 0.f, 0.f};

    // X prefetch: lane(l15,g) reads its own MFMA A-fragment straight from global:
    // x[tile*16+l15][kt*64 + ks*32 + g*8 .. +8)   (two float4 per (tile,ks))
    float4 px[2][2][2];
    auto loadX = [&](int kt) {
#pragma unroll
        for (int j = 0; j < 2; ++j) {
            const int trow = (((j == 0) ? tile0 : tile1) << 4) + l15;
            const float* s_ = xb + trow * C + kt * 64 + (g << 3);
#pragma unroll
            for (int ks = 0; ks < 2; ++ks) {
                px[j][ks][0] = *reinterpret_cast<const float4*>(s_ + (ks << 5));
                px[j][ks][1] = *reinterpret_cast<const float4*>(s_ + (ks << 5) + 4);
            }
        }
    };

    loadX(0);   // in flight during W staging

    // ---- stage ALL W fragments (144 KB) once; the only phase-1 barrier follows ----
    if (USE_WT) {
        const bf16x8* wTv = reinterpret_cast<const bf16x8*>(wT);
#pragma unroll
        for (int ri = 0; ri < 18; ++ri) {
            const int s = (ri << 9) + tid;
            *reinterpret_cast<bf16x8*>(lds + WF_OFF + (s << 4)) = wTv[s];
        }
    } else {
        const float* wm[3] = {Wq, Wk, Wv};
#pragma unroll 1
        for (int ri = 0; ri < 18; ++ri) {
            const int s  = (ri << 9) + tid;
            const int fi = s >> 6, ls = s & 63;
            const int n = fi & 3, q = fi >> 2, m = q % 3, kk = q / 3;
            const int k0 = kk * 32 + ((ls >> 4) << 3);
            const int h  = (n << 4) + (ls & 15);
            bf16x8 v;
#pragma unroll
            for (int j = 0; j < 8; ++j) v[j] = (__bf16)wm[m][(k0 + j) * H + h];
            *reinterpret_cast<bf16x8*>(lds + WF_OFF + (s << 4)) = v;
        }
    }
    __syncthreads();   // barrier 1: WF visible

    // ---------------- Phase 1: barrier-free K-loop ----------------
#pragma unroll 1
    for (int kt = 0; kt < 6; ++kt) {
        bf16x8 af[2][2];
#pragma unroll
        for (int j = 0; j < 2; ++j)
#pragma unroll
            for (int ks = 0; ks < 2; ++ks)
#pragma unroll
                for (int e = 0; e < 4; ++e) {
                    af[j][ks][e]     = (__bf16)px[j][ks][0][e];
                    af[j][ks][e + 4] = (__bf16)px[j][ks][1][e];
                }
        if (kt < 5) loadX(kt + 1);   // prefetch next kt; no barrier will drain it
#pragma unroll
        for (int ks = 0; ks < 2; ++ks)
#pragma unroll
            for (int m = 0; m < 3; ++m)
#pragma unroll
                for (int n = 0; n < 4; ++n) {
                    const int fl = ((kt * 2 + ks) * 3 + m) * 4 + n;
                    const bf16x8 bfr = *reinterpret_cast<const bf16x8*>(
                        lds + WF_OFF + (fl << 10) + (lane << 4));
                    acc[m][0][n] = __builtin_amdgcn_mfma_f32_16x16x32_bf16(af[0][ks], bfr, acc[m][0][n], 0, 0, 0);
                    acc[m][1][n] = __builtin_amdgcn_mfma_f32_16x16x32_bf16(af[1][ks], bfr, acc[m][1][n], 0, 0, 0);
                }
    }
    __syncthreads();   // barrier 2: all WF reads done; region retires to Ks/VT/SCR

    // ---------------- epilogue: K->Ks, V^T->VT, Q->bf16 frags ----------------
    bf16x8 qf[2][2];
    unsigned char* scr = lds + SCR_OFF + (w << 11);
#pragma unroll
    for (int j = 0; j < 2; ++j) {
        const int tb = ((j == 0) ? tile0 : tile1) << 4;
#pragma unroll
        for (int n = 0; n < 4; ++n) {
            const int hcol = (n << 4) + l15;
            bf16x4 pv;
#pragma unroll
            for (int r = 0; r < 4; ++r) pv[r] = (__bf16)acc[2][j][n][r];
            const int trow0 = tb + (g << 2);
            *reinterpret_cast<bf16x4*>(lds + VT_OFF + hcol * 512 + ((2 * trow0) ^ ((hcol & 7) << 4))) = pv;
#pragma unroll
            for (int r = 0; r < 4; ++r) {
                const int trow = trow0 + r;
                *reinterpret_cast<__bf16*>(lds + KS_OFF + trow * 128 + ((2 * hcol) ^ ((trow & 7) << 4))) =
                    (__bf16)acc[1][j][n][r];
            }
        }
        // Q tile j through wave-local scratch -> A-frags
#pragma unroll
        for (int n = 0; n < 4; ++n)
#pragma unroll
            for (int r = 0; r < 4; ++r) {
                const int row = (g << 2) + r;
                *reinterpret_cast<__bf16*>(
                    scr + row * 128 + ((2 * ((n << 4) + l15)) ^ ((row & 7) << 4))) = (__bf16)acc[0][j][n][r];
            }
        qf[j][0] = *reinterpret_cast<const bf16x8*>(
            scr + l15 * 128 + (((g << 4) + 0) ^ ((l15 & 7) << 4)));
        qf[j][1] = *reinterpret_cast<const bf16x8*>(
            scr + l15 * 128 + (((g << 4) + 64) ^ ((l15 & 7) << 4)));
    }
    __syncthreads();   // barrier 3: Ks/VT visible to all waves

    // ---------------- Phase 2: causal attention (no barriers) ----------------
    const float se = 0.051031036307982884f * 1.4426950408889634f;  // 384^-0.5 * log2(e)

    auto attend = [&](int mt, bf16x8 qfa, bf16x8 qfb) {
        const int mtu = __builtin_amdgcn_readfirstlane(mt);
        const int q0  = mt << 4;
        const int qrow = q0 + (g << 2);

        f32x4 o[4];
#pragma unroll
        for (int nh = 0; nh < 4; ++nh) o[nh] = (f32x4){0.f, 0.f, 0.f, 0.f};
        float ssum[4] = {0.f, 0.f, 0.f, 0.f};

#pragma unroll
        for (int kc = 0; kc < 4; ++kc) {
            if (kc <= (mtu >> 2)) {     // wave-uniform causal skip
                f32x4 sb[4];
#pragma unroll
                for (int n4 = 0; n4 < 4; ++n4) sb[n4] = (f32x4){0.f, 0.f, 0.f, 0.f};
#pragma unroll
                for (int ks4 = 0; ks4 < 2; ++ks4) {
                    const bf16x8 qv = (ks4 == 0) ? qfa : qfb;
#pragma unroll
                    for (int n4 = 0; n4 < 4; ++n4) {
                        const int brow = (kc << 6) + (n4 << 4) + l15;
                        const bf16x8 bfr = *reinterpret_cast<const bf16x8*>(
                            lds + KS_OFF + brow * 128 + (((ks4 << 6) + (g << 4)) ^ ((brow & 7) << 4)));
                        sb[n4] = __builtin_amdgcn_mfma_f32_16x16x32_bf16(qv, bfr, sb[n4], 0, 0, 0);
                    }
                }
                // p = exp(s*scale); no max-sub (normalization cancels, |s*scale| small). mask, stage.
#pragma unroll
                for (int n4 = 0; n4 < 4; ++n4) {
                    const int k = (kc << 6) + (n4 << 4) + l15;
#pragma unroll
                    for (int r = 0; r < 4; ++r) {
                        float p = exp2f(sb[n4][r] * se);
                        if (k > qrow + r) p = 0.f;
                        ssum[r] += p;
                        const int prow = (g << 2) + r;
                        *reinterpret_cast<__bf16*>(
                            scr + prow * 128 + ((2 * ((n4 << 4) + l15)) ^ ((prow & 7) << 4))) = (__bf16)p;
                    }
                }
#pragma unroll
                for (int ks4 = 0; ks4 < 2; ++ks4) {
                    const bf16x8 pf = *reinterpret_cast<const bf16x8*>(
                        scr + l15 * 128 + (((ks4 << 6) + (g << 4)) ^ ((l15 & 7) << 4)));
#pragma unroll
                    for (int nh = 0; nh < 4; ++nh) {
                        const int hrow = (nh << 4) + l15;
                        const bf16x8 vb = *reinterpret_cast<const bf16x8*>(
                            lds + VT_OFF + hrow * 512 +
                            (((kc << 7) + (ks4 << 6) + (g << 4)) ^ ((hrow & 7) << 4)));
                        o[nh] = __builtin_amdgcn_mfma_f32_16x16x32_bf16(pf, vb, o[nh], 0, 0, 0);
                    }
                }
            }
        }

#pragma unroll
        for (int d = 1; d < 16; d <<= 1)
#pragma unroll
            for (int r = 0; r < 4; ++r)
                ssum[r] += __shfl_xor(ssum[r], d);

        float inv[4];
#pragma unroll
        for (int r = 0; r < 4; ++r) inv[r] = 1.0f / ssum[r];
        float* ob = out + ((size_t)b * T + q0) * H;
#pragma unroll
        for (int nh = 0; nh < 4; ++nh)
#pragma unroll
            for (int r = 0; r < 4; ++r)
                ob[((g << 2) + r) * H + (nh << 4) + l15] = o[nh][r] * inv[r];
    };

    attend(tile0, qf[0][0], qf[0][1]);
    attend(tile1, qf[1][0], qf[1][1]);
}

extern "C" void kernel_launch(void* const* d_in, const int* in_sizes, int n_in,
                              void* d_out, int out_size, void* d_ws, size_t ws_size,
                              hipStream_t stream) {
    (void)in_sizes; (void)n_in; (void)out_size;
    const float* x  = (const float*)d_in[0];
    const float* Wk = (const float*)d_in[1];
    const float* Wq = (const float*)d_in[2];
    const float* Wv = (const float*)d_in[3];
    float* out = (float*)d_out;
    const size_t wt_bytes = (size_t)9216 * 8 * sizeof(__bf16);
    if (ws_size >= wt_bytes) {
        __bf16* wT = (__bf16*)d_ws;
        prep_w<<<dim3(36), dim3(256), 0, stream>>>(Wq, Wk, Wv, wT);
        head_fused<true><<<dim3(BATCH), dim3(512), 0, stream>>>(x, Wq, Wk, Wv, wT, out);
    } else {
        head_fused<false><<<dim3(BATCH), dim3(512), 0, stream>>>(x, Wq, Wk, Wv, nullptr, out);
    }
}